// Round 2
// baseline (370.227 us; speedup 1.0000x reference)
//
#include <hip/hip_runtime.h>
#include <hip/hip_bf16.h>

// Problem constants (fixed by reference)
#define NB 2048   // batch
#define NF 32     // fields
#define ED 64     // embed dim (d and e)
#define NP 496    // pairs = 32*31/2
#define BM 64     // batch rows per workgroup

typedef __attribute__((ext_vector_type(8))) short short8;
typedef __attribute__((ext_vector_type(4))) float f32x4;

__device__ __forceinline__ unsigned short f2bf(float f) {
    // round-to-nearest-even fp32 -> bf16 (data has no NaN)
    unsigned int u = __builtin_bit_cast(unsigned int, f);
    u += 0x7fffu + ((u >> 16) & 1u);
    return (unsigned short)(u >> 16);
}

__global__ __launch_bounds__(256)
void bilinear_mfma_kernel(const float* __restrict__ emb,
                          const float* __restrict__ W,
                          float* __restrict__ out)
{
    const int bid  = blockIdx.x;
    const int p    = bid >> 5;      // pair index (496)
    const int bblk = bid & 31;      // batch block (2048/64 = 32)
    const int b0   = bblk * BM;

    // pair p -> (fi, fj), triu_indices(32, k=1) row-major order
    int fi = 0, rem = p;
    while (rem >= 31 - fi) { rem -= 31 - fi; ++fi; }
    const int fj = fi + 1 + rem;

    // padded LDS: row stride 72 bf16 = 144 B (multiple of 16 B, breaks
    // the 128B-stride all-rows-same-bank conflict)
    __shared__ unsigned short As[64][72];   // v_i rows: As[b_local][d]
    __shared__ unsigned short Ws[64][72];   // W^T:      Ws[e][d]

    const int tid = threadIdx.x;
    const int r   = tid >> 2;   // 0..63
    const int s   = tid & 3;    // 0..3 (16-float segment)

    // ---- stage A = v_i rows (fp32 -> bf16) ----
    {
        const float4* src = (const float4*)(emb + ((size_t)(b0 + r) * NF + fi) * ED + s * 16);
        #pragma unroll
        for (int q = 0; q < 4; ++q) {
            float4 v = src[q];
            unsigned long long pk =  (unsigned long long)f2bf(v.x)
                                  | ((unsigned long long)f2bf(v.y) << 16)
                                  | ((unsigned long long)f2bf(v.z) << 32)
                                  | ((unsigned long long)f2bf(v.w) << 48);
            *(unsigned long long*)&As[r][s * 16 + q * 4] = pk;
        }
    }

    // ---- stage W[p]^T (fp32 -> bf16, transpose via scattered u16 writes) ----
    {
        const float4* wsrc = (const float4*)(W + (size_t)p * (ED * ED) + r * ED + s * 16);
        #pragma unroll
        for (int q = 0; q < 4; ++q) {
            float4 v = wsrc[q];
            const int e = s * 16 + q * 4;
            Ws[e + 0][r] = f2bf(v.x);
            Ws[e + 1][r] = f2bf(v.y);
            Ws[e + 2][r] = f2bf(v.z);
            Ws[e + 3][r] = f2bf(v.w);
        }
    }

    __syncthreads();

    // ---- MFMA: each wave computes a 16(batch) x 64(e) strip ----
    const int wv   = tid >> 6;      // wave 0..3
    const int lane = tid & 63;
    const int lm   = lane & 15;
    const int h    = lane >> 4;     // K-group 0..3
    const int m    = wv * 16 + lm;  // batch row within block

    // A fragments: lane holds A[m][k0 + h*8 .. +7]; same k-slot mapping used
    // for B below, so MFMA's internal K permutation cancels.
    short8 a0 = *(const short8*)&As[m][h * 8];        // k = 0..31 slice
    short8 a1 = *(const short8*)&As[m][32 + h * 8];   // k = 32..63 slice

    f32x4 acc[4];
    #pragma unroll
    for (int nt = 0; nt < 4; ++nt) {
        acc[nt] = (f32x4){0.f, 0.f, 0.f, 0.f};
        // B fragment: lane holds B[k][n] = W[d=k][e=n] = Ws[n][k], n = nt*16+lm
        short8 b0v = *(const short8*)&Ws[nt * 16 + lm][h * 8];
        short8 b1v = *(const short8*)&Ws[nt * 16 + lm][32 + h * 8];
        acc[nt] = __builtin_amdgcn_mfma_f32_16x16x32_bf16(a0, b0v, acc[nt], 0, 0, 0);
        acc[nt] = __builtin_amdgcn_mfma_f32_16x16x32_bf16(a1, b1v, acc[nt], 0, 0, 0);
    }

    // ---- epilogue: out = proj * v_j (fp32), D layout: col=lane&15, row=h*4+reg ----
    const int row0 = wv * 16 + h * 4;
    #pragma unroll
    for (int nt = 0; nt < 4; ++nt) {
        const int e = nt * 16 + lm;
        #pragma unroll
        for (int rg = 0; rg < 4; ++rg) {
            const int brow = b0 + row0 + rg;
            const float vj = emb[((size_t)brow * NF + fj) * ED + e];
            out[((size_t)brow * NP + p) * ED + e] = acc[nt][rg] * vj;
        }
    }
}

extern "C" void kernel_launch(void* const* d_in, const int* in_sizes, int n_in,
                              void* d_out, int out_size, void* d_ws, size_t ws_size,
                              hipStream_t stream) {
    const float* emb = (const float*)d_in[0];   // [2048][32][64] fp32
    const float* W   = (const float*)d_in[1];   // [496][64][64] fp32
    float* out       = (float*)d_out;           // [2048][496][64] fp32

    dim3 grid(NP * (NB / BM));   // 496 * 32 = 15872
    dim3 block(256);
    bilinear_mfma_kernel<<<grid, block, 0, stream>>>(emb, W, out);
}

// Round 4
// 325.164 us; speedup vs baseline: 1.1386x; 1.1386x over previous
//
#include <hip/hip_runtime.h>
#include <hip/hip_bf16.h>

// Problem constants (fixed by reference)
#define NB 2048   // batch
#define NF 32     // fields
#define ED 64     // embed dim (d and e)
#define NP 496    // pairs = 32*31/2
#define BM 64     // batch rows per workgroup

typedef __attribute__((ext_vector_type(8))) short short8;
typedef __attribute__((ext_vector_type(4))) float f32x4;

__device__ __forceinline__ unsigned short f2bf(float f) {
    // round-to-nearest-even fp32 -> bf16 (data has no NaN)
    unsigned int u = __builtin_bit_cast(unsigned int, f);
    u += 0x7fffu + ((u >> 16) & 1u);
    return (unsigned short)(u >> 16);
}

__device__ __forceinline__ unsigned long long pack4bf(float4 v) {
    return  (unsigned long long)f2bf(v.x)
         | ((unsigned long long)f2bf(v.y) << 16)
         | ((unsigned long long)f2bf(v.z) << 32)
         | ((unsigned long long)f2bf(v.w) << 48);
}

__global__ __launch_bounds__(256)
void bilinear_mfma_kernel(const float* __restrict__ emb,
                          const float* __restrict__ W,
                          float* __restrict__ out)
{
    const int bid  = blockIdx.x;
    const int p    = bid >> 5;      // pair index (496)
    const int bblk = bid & 31;      // batch block (2048/64 = 32)
    const int b0   = bblk * BM;

    // pair p -> (fi, fj), triu_indices(32, k=1) row-major order
    int fi = 0, rem = p;
    while (rem >= 31 - fi) { rem -= 31 - fi; ++fi; }
    const int fj = fi + 1 + rem;

    // 144 B row stride (16B-aligned, breaks power-of-2 bank pattern)
    __shared__ unsigned short As[64][72];   // v_i rows: As[b_local][d]
    __shared__ unsigned short Ws[64][72];   // W^T:      Ws[e][d]
    __shared__ float          Pr[64][68];   // proj transpose buffer (272 B stride)

    const int tid = threadIdx.x;
    const int r   = tid >> 2;   // 0..63 (row)
    const int s   = tid & 3;    // 0..3  (16 B chunk within 64 B block)

    // ---- stage A = v_i rows (fp32 -> bf16). Per-q instruction: lanes s=0..3
    // cover a contiguous 64 B block of each row (granule-perfect). ----
    {
        const float* src = emb + ((size_t)(b0 + r) * NF + fi) * ED;
        #pragma unroll
        for (int q = 0; q < 4; ++q) {
            const int e = q * 16 + s * 4;
            float4 v = *(const float4*)(src + e);
            *(unsigned long long*)&As[r][e] = pack4bf(v);
        }
    }

    // ---- stage W[p]^T (fp32 -> bf16, transpose via scattered u16 writes) ----
    {
        const float* wsrc = W + (size_t)p * (ED * ED) + r * ED;
        #pragma unroll
        for (int q = 0; q < 4; ++q) {
            const int e = q * 16 + s * 4;
            float4 v = *(const float4*)(wsrc + e);
            Ws[e + 0][r] = f2bf(v.x);
            Ws[e + 1][r] = f2bf(v.y);
            Ws[e + 2][r] = f2bf(v.z);
            Ws[e + 3][r] = f2bf(v.w);
        }
    }

    __syncthreads();

    // ---- MFMA: each wave computes a 16(batch) x 64(e) strip ----
    const int wv   = tid >> 6;      // wave 0..3
    const int lane = tid & 63;
    const int lm   = lane & 15;
    const int h    = lane >> 4;     // K-group 0..3
    const int m    = wv * 16 + lm;  // batch row within block

    // Same k-slot mapping for A and B fragments -> internal K permutation cancels.
    short8 a0 = *(const short8*)&As[m][h * 8];        // k = 0..31 slice
    short8 a1 = *(const short8*)&As[m][32 + h * 8];   // k = 32..63 slice

    f32x4 acc[4];
    #pragma unroll
    for (int nt = 0; nt < 4; ++nt) {
        acc[nt] = (f32x4){0.f, 0.f, 0.f, 0.f};
        short8 b0v = *(const short8*)&Ws[nt * 16 + lm][h * 8];
        short8 b1v = *(const short8*)&Ws[nt * 16 + lm][32 + h * 8];
        acc[nt] = __builtin_amdgcn_mfma_f32_16x16x32_bf16(a0, b0v, acc[nt], 0, 0, 0);
        acc[nt] = __builtin_amdgcn_mfma_f32_16x16x32_bf16(a1, b1v, acc[nt], 0, 0, 0);
    }

    // ---- intra-wave transpose: D layout (col=lm, row=h*4+rg) -> row-major LDS.
    // Wave wv writes AND reads only rows [wv*16, wv*16+16): no barrier needed
    // (compiler orders the LDS ops via lgkmcnt; Pr doesn't alias As/Ws). ----
    const int row0 = wv * 16 + h * 4;
    #pragma unroll
    for (int nt = 0; nt < 4; ++nt) {
        #pragma unroll
        for (int rg = 0; rg < 4; ++rg)
            Pr[row0 + rg][nt * 16 + lm] = acc[nt][rg];
    }

    // ---- epilogue: out = proj * v_j, all float4, granule-perfect ----
    const float* vjp = emb + ((size_t)(b0 + r) * NF + fj) * ED;
    float*       op  = out + ((size_t)(b0 + r) * NP + p) * ED;
    #pragma unroll
    for (int q = 0; q < 4; ++q) {
        const int e = q * 16 + s * 4;
        float4 vj = *(const float4*)(vjp + e);
        float4 pr = *(const float4*)&Pr[r][e];
        float4 o;
        o.x = pr.x * vj.x;
        o.y = pr.y * vj.y;
        o.z = pr.z * vj.z;
        o.w = pr.w * vj.w;
        *(float4*)(op + e) = o;
    }
}

extern "C" void kernel_launch(void* const* d_in, const int* in_sizes, int n_in,
                              void* d_out, int out_size, void* d_ws, size_t ws_size,
                              hipStream_t stream) {
    const float* emb = (const float*)d_in[0];   // [2048][32][64] fp32
    const float* W   = (const float*)d_in[1];   // [496][64][64] fp32
    float* out       = (float*)d_out;           // [2048][496][64] fp32

    dim3 grid(NP * (NB / BM));   // 496 * 32 = 15872
    dim3 block(256);
    bilinear_mfma_kernel<<<grid, block, 0, stream>>>(emb, W, out);
}

// Round 7
// 290.477 us; speedup vs baseline: 1.2745x; 1.1194x over previous
//
#include <hip/hip_runtime.h>
#include <hip/hip_bf16.h>

// Problem constants (fixed by reference)
#define NB 2048   // batch
#define NF 32     // fields
#define ED 64     // embed dim (d and e)
#define NP 496    // pairs = 32*31/2
#define BM 64     // batch rows per workgroup

typedef __attribute__((ext_vector_type(8))) short short8;
typedef __attribute__((ext_vector_type(4))) float f32x4;
typedef unsigned long long u64;

__device__ __forceinline__ unsigned short f2bf(float f) {
    // round-to-nearest-even fp32 -> bf16 (data has no NaN)
    unsigned int u = __builtin_bit_cast(unsigned int, f);
    u += 0x7fffu + ((u >> 16) & 1u);
    return (unsigned short)(u >> 16);
}
__device__ __forceinline__ float bf2f(unsigned short h) {
    unsigned int u = ((unsigned int)h) << 16;
    return __builtin_bit_cast(float, u);
}

// ---- prep 1: Wt[p][e][d] = bf16(W[p][d][e])  (one block per pair) ----
__global__ __launch_bounds__(256)
void prep_wt(const float* __restrict__ W, unsigned short* __restrict__ Wt)
{
    __shared__ float Ls[64][65];           // padded: column reads ~2-way = free
    const int p = blockIdx.x, t = threadIdx.x;
    const int r = t >> 2, s = t & 3;
    const float* src = W + (size_t)p * 4096 + (size_t)r * 64;
    #pragma unroll
    for (int q = 0; q < 4; ++q) {
        const int e = q * 16 + s * 4;
        float4 v = *(const float4*)(src + e);
        Ls[r][e + 0] = v.x; Ls[r][e + 1] = v.y;
        Ls[r][e + 2] = v.z; Ls[r][e + 3] = v.w;
    }
    __syncthreads();
    unsigned short* dst = Wt + (size_t)p * 4096 + (size_t)r * 64;  // row e = r
    #pragma unroll
    for (int q = 0; q < 4; ++q) {
        const int d0 = q * 16 + s * 4;
        u64 pk =  (u64)f2bf(Ls[d0 + 0][r])
               | ((u64)f2bf(Ls[d0 + 1][r]) << 16)
               | ((u64)f2bf(Ls[d0 + 2][r]) << 32)
               | ((u64)f2bf(Ls[d0 + 3][r]) << 48);
        *(u64*)(dst + d0) = pk;
    }
}

// ---- prep 2: Eb = bf16(emb), elementwise (8 floats/thread) ----
__global__ __launch_bounds__(256)
void prep_emb(const float* __restrict__ emb, unsigned short* __restrict__ Eb)
{
    const size_t g = (size_t)blockIdx.x * 256 + threadIdx.x;
    const float* src = emb + g * 8;
    float4 v0 = *(const float4*)src;
    float4 v1 = *(const float4*)(src + 4);
    short8 o;
    o[0] = (short)f2bf(v0.x); o[1] = (short)f2bf(v0.y);
    o[2] = (short)f2bf(v0.z); o[3] = (short)f2bf(v0.w);
    o[4] = (short)f2bf(v1.x); o[5] = (short)f2bf(v1.y);
    o[6] = (short)f2bf(v1.z); o[7] = (short)f2bf(v1.w);
    *(short8*)(Eb + g * 8) = o;
}

// ---- main: pure bf16 staging + MFMA + fp32 epilogue ----
__global__ __launch_bounds__(256)
void bilinear_main(const unsigned short* __restrict__ Eb,
                   const unsigned short* __restrict__ Wt,
                   float* __restrict__ out)
{
    const int bid  = blockIdx.x;
    const int p    = bid >> 5;
    const int bblk = bid & 31;
    const int b0   = bblk * BM;

    int fi = 0, rem = p;
    while (rem >= 31 - fi) { rem -= 31 - fi; ++fi; }
    const int fj = fi + 1 + rem;

    __shared__ unsigned short As[64][72];   // v_i rows (144 B stride, 16B-aligned)
    __shared__ unsigned short Ws[64][72];   // W^T rows
    __shared__ float          Pr[64][68];   // proj transpose (272 B stride)

    const int tid = threadIdx.x;
    const int r   = tid >> 2;   // 0..63
    const int s   = tid & 3;    // 0..3

    // A-stage: vectorized bf16 copy, granule-perfect (4 lanes x 16 B = 64 B)
    {
        const unsigned short* src = Eb + ((size_t)(b0 + r) * NF + fi) * ED;
        *(short8*)&As[r][s * 8]      = *(const short8*)(src + s * 8);
        *(short8*)&As[r][32 + s * 8] = *(const short8*)(src + 32 + s * 8);
    }
    // W-stage: Wt rows are already transposed+converted
    {
        const unsigned short* src = Wt + (size_t)p * (ED * ED) + (size_t)r * ED;
        *(short8*)&Ws[r][s * 8]      = *(const short8*)(src + s * 8);
        *(short8*)&Ws[r][32 + s * 8] = *(const short8*)(src + 32 + s * 8);
    }
    __syncthreads();

    const int wv   = tid >> 6;
    const int lane = tid & 63;
    const int lm   = lane & 15;
    const int h    = lane >> 4;
    const int m    = wv * 16 + lm;

    short8 a0 = *(const short8*)&As[m][h * 8];
    short8 a1 = *(const short8*)&As[m][32 + h * 8];

    f32x4 acc[4];
    #pragma unroll
    for (int nt = 0; nt < 4; ++nt) {
        acc[nt] = (f32x4){0.f, 0.f, 0.f, 0.f};
        short8 b0v = *(const short8*)&Ws[nt * 16 + lm][h * 8];
        short8 b1v = *(const short8*)&Ws[nt * 16 + lm][32 + h * 8];
        acc[nt] = __builtin_amdgcn_mfma_f32_16x16x32_bf16(a0, b0v, acc[nt], 0, 0, 0);
        acc[nt] = __builtin_amdgcn_mfma_f32_16x16x32_bf16(a1, b1v, acc[nt], 0, 0, 0);
    }

    // intra-wave transpose (wave-private rows, no barrier needed)
    const int row0 = wv * 16 + h * 4;
    #pragma unroll
    for (int nt = 0; nt < 4; ++nt) {
        #pragma unroll
        for (int rg = 0; rg < 4; ++rg)
            Pr[row0 + rg][nt * 16 + lm] = acc[nt][rg];
    }

    // epilogue: out = proj * v_j (vj from bf16), all vector ops
    const unsigned short* vjp = Eb + ((size_t)(b0 + r) * NF + fj) * ED;
    float* op = out + ((size_t)(b0 + r) * NP + p) * ED;
    #pragma unroll
    for (int hb = 0; hb < 2; ++hb) {
        const int e0 = hb * 32 + s * 8;
        short8 vjv = *(const short8*)(vjp + e0);
        float4 p0 = *(const float4*)&Pr[r][e0];
        float4 p1 = *(const float4*)&Pr[r][e0 + 4];
        float4 o0, o1;
        o0.x = p0.x * bf2f((unsigned short)vjv[0]);
        o0.y = p0.y * bf2f((unsigned short)vjv[1]);
        o0.z = p0.z * bf2f((unsigned short)vjv[2]);
        o0.w = p0.w * bf2f((unsigned short)vjv[3]);
        o1.x = p1.x * bf2f((unsigned short)vjv[4]);
        o1.y = p1.y * bf2f((unsigned short)vjv[5]);
        o1.z = p1.z * bf2f((unsigned short)vjv[6]);
        o1.w = p1.w * bf2f((unsigned short)vjv[7]);
        *(float4*)(op + e0)     = o0;
        *(float4*)(op + e0 + 4) = o1;
    }
}

// ---- fallback (round-4 validated kernel) if ws too small ----
__global__ __launch_bounds__(256)
void bilinear_fallback(const float* __restrict__ emb,
                       const float* __restrict__ W,
                       float* __restrict__ out)
{
    const int bid  = blockIdx.x;
    const int p    = bid >> 5;
    const int bblk = bid & 31;
    const int b0   = bblk * BM;
    int fi = 0, rem = p;
    while (rem >= 31 - fi) { rem -= 31 - fi; ++fi; }
    const int fj = fi + 1 + rem;

    __shared__ unsigned short As[64][72];
    __shared__ unsigned short Ws[64][72];
    __shared__ float          Pr[64][68];

    const int tid = threadIdx.x;
    const int r   = tid >> 2;
    const int s   = tid & 3;
    {
        const float* src = emb + ((size_t)(b0 + r) * NF + fi) * ED;
        #pragma unroll
        for (int q = 0; q < 4; ++q) {
            const int e = q * 16 + s * 4;
            float4 v = *(const float4*)(src + e);
            u64 pk =  (u64)f2bf(v.x) | ((u64)f2bf(v.y) << 16)
                   | ((u64)f2bf(v.z) << 32) | ((u64)f2bf(v.w) << 48);
            *(u64*)&As[r][e] = pk;
        }
    }
    {
        const float* wsrc = W + (size_t)p * (ED * ED) + r * ED;
        #pragma unroll
        for (int q = 0; q < 4; ++q) {
            const int e = q * 16 + s * 4;
            float4 v = *(const float4*)(wsrc + e);
            Ws[e + 0][r] = f2bf(v.x); Ws[e + 1][r] = f2bf(v.y);
            Ws[e + 2][r] = f2bf(v.z); Ws[e + 3][r] = f2bf(v.w);
        }
    }
    __syncthreads();
    const int wv = tid >> 6, lane = tid & 63, lm = lane & 15, h = lane >> 4;
    const int m = wv * 16 + lm;
    short8 a0 = *(const short8*)&As[m][h * 8];
    short8 a1 = *(const short8*)&As[m][32 + h * 8];
    f32x4 acc[4];
    #pragma unroll
    for (int nt = 0; nt < 4; ++nt) {
        acc[nt] = (f32x4){0.f, 0.f, 0.f, 0.f};
        short8 b0v = *(const short8*)&Ws[nt * 16 + lm][h * 8];
        short8 b1v = *(const short8*)&Ws[nt * 16 + lm][32 + h * 8];
        acc[nt] = __builtin_amdgcn_mfma_f32_16x16x32_bf16(a0, b0v, acc[nt], 0, 0, 0);
        acc[nt] = __builtin_amdgcn_mfma_f32_16x16x32_bf16(a1, b1v, acc[nt], 0, 0, 0);
    }
    const int row0 = wv * 16 + h * 4;
    #pragma unroll
    for (int nt = 0; nt < 4; ++nt)
        #pragma unroll
        for (int rg = 0; rg < 4; ++rg)
            Pr[row0 + rg][nt * 16 + lm] = acc[nt][rg];
    const float* vjp = emb + ((size_t)(b0 + r) * NF + fj) * ED;
    float* op = out + ((size_t)(b0 + r) * NP + p) * ED;
    #pragma unroll
    for (int q = 0; q < 4; ++q) {
        const int e = q * 16 + s * 4;
        float4 vj = *(const float4*)(vjp + e);
        float4 pr = *(const float4*)&Pr[r][e];
        float4 o = { pr.x * vj.x, pr.y * vj.y, pr.z * vj.z, pr.w * vj.w };
        *(float4*)(op + e) = o;
    }
}

extern "C" void kernel_launch(void* const* d_in, const int* in_sizes, int n_in,
                              void* d_out, int out_size, void* d_ws, size_t ws_size,
                              hipStream_t stream) {
    const float* emb = (const float*)d_in[0];   // [2048][32][64] fp32
    const float* W   = (const float*)d_in[1];   // [496][64][64] fp32
    float* out       = (float*)d_out;           // [2048][496][64] fp32

    const size_t wt_bytes = (size_t)NP * ED * ED * 2;        // 4,063,232
    const size_t eb_bytes = (size_t)NB * NF * ED * 2;        // 8,388,608
    if (ws_size >= wt_bytes + eb_bytes) {
        unsigned short* Wt = (unsigned short*)d_ws;
        unsigned short* Eb = (unsigned short*)((char*)d_ws + wt_bytes);
        prep_wt <<<NP, 256, 0, stream>>>(W, Wt);
        prep_emb<<<(NB * NF * ED / 8) / 256, 256, 0, stream>>>(emb, Eb);  // 2048 blocks
        bilinear_main<<<NP * (NB / BM), 256, 0, stream>>>(Eb, Wt, out);
    } else {
        bilinear_fallback<<<NP * (NB / BM), 256, 0, stream>>>(emb, W, out);
    }
}